// Round 20
// baseline (243.378 us; speedup 1.0000x reference)
//
#include <hip/hip_runtime.h>
#include <hip/hip_bf16.h>
#include <hip/hip_fp16.h>

// ---------------------------------------------------------------------------
// GCN-align highway:
//   xw = X @ w2                           (MFMA f16 GEMM, f32 accumulate)
//   a  = relu(A @ w1); b = relu(A @ xw)   (fused dual CSR spmm)
//   T  = sigmoid(b @ wg); y = T*a + (1-T)*b  (fused into spmm epilogue)
//   out = A @ y                           (CSR spmm, f16 gathers, f32 out)
// Gathered operands: w1 fp8 e4m3 x128 (128B row = one line), xw/y f16.
// Metadata 4B: col17|val15 fixed-point.
// CSR build: ZERO global atomics. Counting sort, 512-row buckets, CHUNK=8192
// (round-19: longer scatter runs -> L2 write coalescing; now ~42 recs/336B).
// k_sortscan eliminated: each sort3 block recomputes the 196-wide bucket-base
// scan in LDS (parallel, ~free) -- one fewer launch/serialization.
// L2-miss path wall ~3.3-3.5 TB/s, linear in bytes (rounds 5/7).
// ---------------------------------------------------------------------------

using f16x8 = __attribute__((ext_vector_type(8))) _Float16;
using f32x4 = __attribute__((ext_vector_type(4))) float;
using f32x2 = __attribute__((ext_vector_type(2))) float;

#define W1SCALE 128.0f
#define VSCL    3.0517578125e-05f       // 1/32768 (15-bit fixed-point)
#define AF      (VSCL / 128.0f)         // a-path rescale: vq-sum * fp8(x128)
#define CHUNK   8192                    // edges per sort block
#define BROWS   512                     // rows per coarse bucket
#define BSHIFT  9
#define MAXNB   256                     // max buckets (N <= 131072)

// ---------------- colscan: per-bucket scan of partials over chunks ---------
// wave w of block handles bucket b = blockIdx*4+w. Reads partials[ci][b]
// (scattered), writes colscanT[b][ci] (coalesced) = exclusive prefix;
// bktfill[b] = total.
__global__ __launch_bounds__(256) void k_colscan(const int* __restrict__ partials,
                                                 int* __restrict__ colscanT,
                                                 int* __restrict__ bktfill,
                                                 int nb, int sb) {
  int lane = threadIdx.x & 63, w = threadIdx.x >> 6;
  int b = blockIdx.x * 4 + w;
  if (b >= nb) return;
  int carry = 0;
  for (int ci0 = 0; ci0 < sb; ci0 += 64) {
    int ci = ci0 + lane;
    int v = (ci < sb) ? partials[(size_t)ci * nb + b] : 0;
    int incl = v;
#pragma unroll
    for (int off = 1; off < 64; off <<= 1) {
      int t = __shfl_up(incl, off);
      if (lane >= off) incl += t;
    }
    if (ci < sb) colscanT[(size_t)b * sb + ci] = carry + incl - v;
    carry += __shfl(incl, 63);
  }
  if (lane == 0) bktfill[b] = carry;
}

// ---------------- scatter3: edges -> bucket-partitioned staging ------------
// Block bi re-streams chunk bi; cursor[bkt] = bkt*cap + colscanT[bkt][bi]
// precomputed (no global atomics); LDS atomic arrival order within chunk.
__global__ __launch_bounds__(256) void k_scatter3(const int* __restrict__ Ar,
                                                  const int* __restrict__ Ac,
                                                  const float* __restrict__ Av,
                                                  const int* __restrict__ colscanT,
                                                  uint2* __restrict__ tmp,
                                                  int nnz, int nb, int cap, int sb) {
  __shared__ int cursor[MAXNB];
  int tid = threadIdx.x, bi = blockIdx.x;
  for (int t = tid; t < nb; t += 256)
    cursor[t] = t * cap + colscanT[(size_t)t * sb + bi];
  __syncthreads();
  int base = bi * CHUNK;
  int cnt = min(CHUNK, nnz - base);
  for (int it = 0; it < CHUNK / 256; ++it) {
    int k = it * 256 + tid;
    if (k < cnt) {
      int i = base + k;
      int r = Ar[i];
      int bkt = r >> BSHIFT;
      unsigned uq = (unsigned)fminf(Av[i] * 32768.f + 0.5f, 32767.f);
      int pos = atomicAdd(&cursor[bkt], 1);
      if (pos < (bkt + 1) * cap)
        tmp[pos] = make_uint2(((unsigned)Ac[i] << 15) | uq, (unsigned)r);
    }
  }
}

// ---------------- sort3: per-bucket CSR finalize (two-pass, LDS only) ------
// Each block recomputes the bucket-base scan of bktfill[0..nb) in LDS (cheap,
// parallel) -- replaces the former k_sortscan launch.
__global__ __launch_bounds__(1024) void k_sort3(const uint2* __restrict__ tmp,
                                                const int* __restrict__ bktfill,
                                                unsigned* __restrict__ ccv,
                                                int* __restrict__ rp,
                                                int n, int cap, int nb, int nnz) {
  __shared__ int rcnt[BROWS];
  __shared__ int rbase[BROWS];
  __shared__ int bf[MAXNB];
  int b = blockIdx.x, tid = threadIdx.x;

  // inline bucket-base scan (Hillis-Steele over nb <= 256)
  if (tid < nb) bf[tid] = bktfill[tid];
  __syncthreads();
  for (int off = 1; off < nb; off <<= 1) {
    int v = 0;
    if (tid < nb) {
      v = bf[tid];
      if (tid >= off) v += bf[tid - off];
    }
    __syncthreads();
    if (tid < nb) bf[tid] = v;
    __syncthreads();
  }
  int fillb = bktfill[b];
  int cnt = min(fillb, cap);
  int bbase = bf[b] - fillb;  // exclusive prefix
  const uint2* src = tmp + (size_t)b * cap;
  if (b == 0 && tid == 0) rp[n] = nnz;

  if (tid < BROWS) rcnt[tid] = 0;
  __syncthreads();

  // pass A: count local rows
  for (int i = tid; i < cnt; i += 1024)
    atomicAdd(&rcnt[src[i].y & (BROWS - 1)], 1);
  __syncthreads();

  // Hillis-Steele inclusive scan of rcnt[BROWS]
  int own = (tid < BROWS) ? rcnt[tid] : 0;
  for (int off = 1; off < BROWS; off <<= 1) {
    int v = 0;
    if (tid < BROWS) {
      v = rcnt[tid];
      if (tid >= off) v += rcnt[tid - off];
    }
    __syncthreads();
    if (tid < BROWS) rcnt[tid] = v;
    __syncthreads();
  }
  if (tid < BROWS) {
    int ex = rcnt[tid] - own;  // exclusive
    rbase[tid] = ex;
    int row = b * BROWS + tid;
    if (row < n) rp[row] = bbase + ex;
  }
  __syncthreads();
  if (tid < BROWS) rcnt[tid] = rbase[tid];  // reset as cursors
  __syncthreads();

  // pass B: re-read (L2-hot) and place
  for (int i = tid; i < cnt; i += 1024) {
    uint2 rr = src[i];
    int p = atomicAdd(&rcnt[rr.y & (BROWS - 1)], 1);
    ccv[bbase + p] = rr.x;
  }
}

// ---------------- MFMA GEMM + fused w1->fp8 + fused sort P1 (hist only) ----
// Blocks [0, sortB): P1 LDS hist -> coalesced partials store (NO atomics).
// Blocks [sortB, ...): GEMM (4 waves, 256 rows each).
#define BM 256
__global__ __launch_bounds__(256) void k_gemm(const float* __restrict__ X,
                                              const float* __restrict__ w1,
                                              const float* __restrict__ W,
                                              __half* __restrict__ xw16,
                                              unsigned char* __restrict__ w1f8, int n,
                                              const int* __restrict__ Ar,
                                              int* __restrict__ partials,
                                              int nnz, int nb, int sortB) {
  __shared__ char smem[32768];
  int tid = threadIdx.x;

  if (blockIdx.x < sortB) {  // ---- sort P1: per-chunk histogram ----
    int* hist = (int*)smem;  // nb ints
    int bi = blockIdx.x;
    int base = bi * CHUNK;
    int cnt = min(CHUNK, nnz - base);
    for (int t = tid; t < nb; t += 256) hist[t] = 0;
    __syncthreads();
    for (int it = 0; it < CHUNK / 256; ++it) {
      int k = it * 256 + tid;
      if (k < cnt) atomicAdd(&hist[Ar[base + k] >> BSHIFT], 1);
    }
    __syncthreads();
    for (int t = tid; t < nb; t += 256)
      partials[(size_t)bi * nb + t] = hist[t];  // coalesced plain store
    return;
  }

  // ---- GEMM part ----
  __half* lds = (__half*)smem;  // 32 KB swizzled W^T
  // stage w2: thread t handles 8 k-elements of column nn
  for (int t = tid; t < 2048; t += 256) {
    int nn = t >> 4, kg = t & 15;
    union { _Float16 h[8]; uint4 u; } u;
#pragma unroll
    for (int j = 0; j < 8; ++j) u.h[j] = (_Float16)W[(kg * 8 + j) * 128 + nn];
    int byte = nn * 256 + ((kg * 16) ^ ((nn & 7) << 4));
    *(uint4*)((char*)lds + byte) = u.u;
  }

  // fused w1 -> fp8(x128) for this block's rows
  long r0 = (long)(blockIdx.x - sortB) * BM;
  for (int i = tid; i < BM * 16; i += 256) {
    int rr = i >> 4, gg = i & 15;
    long r = r0 + rr;
    if (r < n) {
      const float* src = w1 + r * 128 + gg * 8;
      float4 f0 = *(const float4*)src;
      float4 f1 = *(const float4*)(src + 4);
      int lo = __builtin_amdgcn_cvt_pk_fp8_f32(f0.x * W1SCALE, f0.y * W1SCALE, 0, false);
      lo = __builtin_amdgcn_cvt_pk_fp8_f32(f0.z * W1SCALE, f0.w * W1SCALE, lo, true);
      int hi = __builtin_amdgcn_cvt_pk_fp8_f32(f1.x * W1SCALE, f1.y * W1SCALE, 0, false);
      hi = __builtin_amdgcn_cvt_pk_fp8_f32(f1.z * W1SCALE, f1.w * W1SCALE, hi, true);
      uint2 st = {(unsigned)lo, (unsigned)hi};
      *(uint2*)(w1f8 + r * 128 + gg * 8) = st;
    }
  }
  __syncthreads();

  int wid = tid >> 6, lane = tid & 63;
  int g = lane >> 4, lm = lane & 15;
  long rowbase = r0 + wid * 64;

  // A fragments: afr[m][kk], lane holds row (lm), k = kk*32 + g*8 + j
  f16x8 afr[4][4];
#pragma unroll
  for (int m = 0; m < 4; ++m) {
    long r = rowbase + m * 16 + lm;
    if (r >= n) r = n - 1;
    const float* xp = X + r * 128 + g * 8;
#pragma unroll
    for (int kk = 0; kk < 4; ++kk) {
      float4 lo = *(const float4*)(xp + kk * 32);
      float4 hi = *(const float4*)(xp + kk * 32 + 4);
      f16x8 a;
      a[0] = (_Float16)lo.x; a[1] = (_Float16)lo.y;
      a[2] = (_Float16)lo.z; a[3] = (_Float16)lo.w;
      a[4] = (_Float16)hi.x; a[5] = (_Float16)hi.y;
      a[6] = (_Float16)hi.z; a[7] = (_Float16)hi.w;
      afr[m][kk] = a;
    }
  }

#pragma unroll
  for (int nt = 0; nt < 8; ++nt) {
    int nn = nt * 16 + lm;
    int sw = (nn & 7) << 4;
    f16x8 bfr[4];
#pragma unroll
    for (int kk = 0; kk < 4; ++kk) {
      int byte = nn * 256 + ((kk * 64 + g * 16) ^ sw);
      bfr[kk] = *(f16x8*)((char*)lds + byte);
    }
#pragma unroll
    for (int m = 0; m < 4; ++m) {
      f32x4 acc = {0.f, 0.f, 0.f, 0.f};
#pragma unroll
      for (int kk = 0; kk < 4; ++kk)
        acc = __builtin_amdgcn_mfma_f32_16x16x32_f16(afr[m][kk], bfr[kk], acc, 0, 0, 0);
      // D: col = nn, row = rowbase + m*16 + g*4 + r (2B stores; L2 coalesces)
#pragma unroll
      for (int r = 0; r < 4; ++r) {
        long row = rowbase + m * 16 + g * 4 + r;
        if (row < n) xw16[row * 128 + nn] = __float2half(acc[r]);
      }
    }
  }
}

// ---------------- fused dual spmm + relu + highway gate --------------------
// one wave per row. Lane owns features {2l,2l+1}: per edge one full-wave
// ushort load (fp8 w1 row, 128B) + one full-wave uint load (f16 xw row,
// 256B). Branchless; scalar-broadcast metadata.
__global__ __launch_bounds__(256) void k_spmm_ab(const int* __restrict__ rp,
                                                 const unsigned* __restrict__ ccv,
                                                 const unsigned char* __restrict__ w1f8,
                                                 const __half* __restrict__ xw16,
                                                 const float* __restrict__ wg,
                                                 __half* __restrict__ y16, int n) {
  int row = (int)((blockIdx.x * 256 + threadIdx.x) >> 6);
  int lane = threadIdx.x & 63;
  if (row >= n) return;
  int s = rp[row], e = rp[row + 1];
  const unsigned char* aptr = w1f8 + lane * 2;   // 2 fp8 features per lane
  const __half* bptr = xw16 + lane * 2;          // 2 f16 features per lane
  float aa0 = 0.f, aa1 = 0.f, bb0 = 0.f, bb1 = 0.f;

#define AB_EDGE(J)                                                         \
  {                                                                        \
    unsigned mm = (unsigned)__builtin_amdgcn_readlane((int)mr, (J));       \
    unsigned col = mm >> 15;                                               \
    float vq = (float)(mm & 0x7fffu);                                      \
    unsigned ua = *(const unsigned short*)(aptr + (size_t)col * 128);      \
    unsigned ub = *(const unsigned*)((const char*)bptr + (size_t)col * 256); \
    f32x2 fa = __builtin_amdgcn_cvt_pk_f32_fp8(ua, false);                 \
    float2 fb = __half22float2(*(__half2*)&ub);                            \
    aa0 = fmaf(vq, fa[0], aa0); aa1 = fmaf(vq, fa[1], aa1);                \
    bb0 = fmaf(vq, fb.x, bb0); bb1 = fmaf(vq, fb.y, bb1);                  \
  }

  for (int chunk = s; chunk < e; chunk += 64) {
    int idx = chunk + lane;
    unsigned mr = (idx < e) ? ccv[idx] : 0u;
    int cl = min(64, e - chunk);
    int j = 0;
    for (; j + 3 < cl; j += 4) {
      AB_EDGE(j) AB_EDGE(j + 1) AB_EDGE(j + 2) AB_EDGE(j + 3)
    }
    for (; j < cl; ++j) AB_EDGE(j)
  }
#undef AB_EDGE

  // rescale + relu
  float a0 = fmaxf(aa0 * AF, 0.f), a1 = fmaxf(aa1 * AF, 0.f);
  float b0 = fmaxf(bb0 * VSCL, 0.f), b1 = fmaxf(bb1 * VSCL, 0.f);

  // gate: T = sigmoid(dot(b, wg)) -- full-wave reduce
  float2 wgv = *(const float2*)(wg + lane * 2);
  float part = b0 * wgv.x + b1 * wgv.y;
#pragma unroll
  for (int off = 32; off > 0; off >>= 1) part += __shfl_xor(part, off);
  float T = 1.f / (1.f + __expf(-part));
  float u = 1.f - T;

  union { __half2 h2; unsigned uu; } st;
  st.h2 = __floats2half2_rn(T * a0 + u * b0, T * a1 + u * b1);
  *(unsigned*)(y16 + (size_t)row * 128 + lane * 2) = st.uu;
}

// ---------------- final spmm: out = A @ y ----------------------------------
// one wave per row; full wave gathers one y16 row per edge (64 lanes x 4B).
__global__ __launch_bounds__(256) void k_spmm_out(const int* __restrict__ rp,
                                                  const unsigned* __restrict__ ccv,
                                                  const __half* __restrict__ y16,
                                                  float* __restrict__ out, int n) {
  int row = (int)((blockIdx.x * 256 + threadIdx.x) >> 6);
  int lane = threadIdx.x & 63;
  if (row >= n) return;
  int s = rp[row], e = rp[row + 1];
  const __half* ysub = y16 + lane * 2;
  float ac0 = 0.f, ac1 = 0.f;

#define OUT_EDGE(J)                                                        \
  {                                                                        \
    unsigned mm = (unsigned)__builtin_amdgcn_readlane((int)mr, (J));       \
    unsigned col = mm >> 15;                                               \
    float vq = (float)(mm & 0x7fffu);                                      \
    float2 f = __half22float2(*(const __half2*)((const char*)ysub + (size_t)col * 256)); \
    ac0 = fmaf(vq, f.x, ac0); ac1 = fmaf(vq, f.y, ac1);                    \
  }

  for (int chunk = s; chunk < e; chunk += 64) {
    int idx = chunk + lane;
    unsigned mr = (idx < e) ? ccv[idx] : 0u;
    int cl = min(64, e - chunk);
    int j = 0;
    for (; j + 3 < cl; j += 4) {
      OUT_EDGE(j) OUT_EDGE(j + 1) OUT_EDGE(j + 2) OUT_EDGE(j + 3)
    }
    for (; j < cl; ++j) OUT_EDGE(j)
  }
#undef OUT_EDGE

  union { float2 f2; long long ll; } ov;
  ov.f2.x = ac0 * VSCL;
  ov.f2.y = ac1 * VSCL;
  __builtin_nontemporal_store(ov.ll, (long long*)(out + (size_t)row * 128 + lane * 2));
}

// ---------------------------------------------------------------------------
extern "C" void kernel_launch(void* const* d_in, const int* in_sizes, int n_in,
                              void* d_out, int out_size, void* d_ws, size_t ws_size,
                              hipStream_t stream) {
  const float* X  = (const float*)d_in[0];
  const float* w1 = (const float*)d_in[1];
  const float* w2 = (const float*)d_in[2];
  const float* wg = (const float*)d_in[3];
  const float* Av = (const float*)d_in[4];
  const int*   Ar = (const int*)d_in[5];
  const int*   Ac = (const int*)d_in[6];
  float* out = (float*)d_out;
  int N   = in_sizes[0] / 128;
  int NNZ = in_sizes[4];

  int NB    = (N + BROWS - 1) >> BSHIFT;    // 512-row buckets
  int sortB = (NNZ + CHUNK - 1) / CHUNK;    // chunks
  int cap   = (NNZ / NB) * 3 / 2 + 256;     // bucket staging capacity

  char* p = (char*)d_ws;
  auto alloc = [&](size_t b) {
    char* r = p;
    p += (b + 255) & ~(size_t)255;
    return r;
  };
  int*            rp       = (int*)alloc((size_t)(N + 1) * 4);
  int*            partials = (int*)alloc((size_t)sortB * NB * 4);
  int*            colscanT = (int*)alloc((size_t)NB * sortB * 4);
  int*            bktfill  = (int*)alloc((size_t)NB * 4);
  uint2*          tmp      = (uint2*)alloc((size_t)NB * cap * 8);
  unsigned*       ccv      = (unsigned*)alloc((size_t)NNZ * 4);
  __half*         xw16     = (__half*)alloc((size_t)N * 128 * 2);
  unsigned char*  w1f8     = (unsigned char*)alloc((size_t)N * 128);
  __half*         y16      = (__half*)alloc((size_t)N * 128 * 2);

  int gemmB = (N + BM - 1) / BM;
  k_gemm<<<sortB + gemmB, 256, 0, stream>>>(X, w1, w2, xw16, w1f8, N,
                                            Ar, partials, NNZ, NB, sortB);
  k_colscan<<<(NB + 3) / 4, 256, 0, stream>>>(partials, colscanT, bktfill, NB, sortB);
  k_scatter3<<<sortB, 256, 0, stream>>>(Ar, Ac, Av, colscanT, tmp, NNZ, NB, cap, sortB);
  k_sort3<<<NB, 1024, 0, stream>>>(tmp, bktfill, ccv, rp, N, cap, NB, NNZ);
  int wb = (N + 3) / 4;  // one 64-lane wave per row, 4 rows per 256-thread block
  k_spmm_ab<<<wb, 256, 0, stream>>>(rp, ccv, w1f8, xw16, wg, y16, N);
  k_spmm_out<<<wb, 256, 0, stream>>>(rp, ccv, y16, out, N);
}

// Round 21
// 223.480 us; speedup vs baseline: 1.0890x; 1.0890x over previous
//
#include <hip/hip_runtime.h>
#include <hip/hip_bf16.h>
#include <hip/hip_fp16.h>

// ---------------------------------------------------------------------------
// GCN-align highway:
//   xw = X @ w2                           (MFMA f16 GEMM, f32 accumulate)
//   a  = relu(A @ w1); b = relu(A @ xw)   (fused dual CSR spmm)
//   T  = sigmoid(b @ wg); y = T*a + (1-T)*b  (fused into spmm epilogue)
//   out = A @ y                           (CSR spmm, int8 gathers, f32 out)
// Gathered operands: w1 fp8 e4m3 x128 (128B row = one line), xw f16 (gate
// path is error-amplifying, stays f16), y as per-row-scaled INT8 (128B row =
// one line; absolute error <= rowmax/510 -- NOT fp8, whose relative error at
// |y|~8 would blow up). Metadata 4B: col17|val15 fixed-point.
// CSR build (round-19 config, best measured): zero global atomics, counting
// sort, 512-row buckets, CHUNK=4096, separate sortscan (round-20 merge was
// neutral/negative -> reverted).
// L2-miss path wall ~3.3-3.5 TB/s, linear in bytes (rounds 5/7).
// ---------------------------------------------------------------------------

using f16x8 = __attribute__((ext_vector_type(8))) _Float16;
using f32x4 = __attribute__((ext_vector_type(4))) float;
using f32x2 = __attribute__((ext_vector_type(2))) float;

#define W1SCALE 128.0f
#define VSCL    3.0517578125e-05f       // 1/32768 (15-bit fixed-point)
#define AF      (VSCL / 128.0f)         // a-path rescale: vq-sum * fp8(x128)
#define CHUNK   4096                    // edges per sort block
#define BROWS   512                     // rows per coarse bucket
#define BSHIFT  9
#define MAXNB   256                     // max buckets (N <= 131072)

// ---------------- block-wide inclusive scan helper ----------------
__device__ __forceinline__ int block_incl_scan(int v, int* wsum) {
  int tid = threadIdx.x, lane = tid & 63, wid = tid >> 6;
  int incl = v;
#pragma unroll
  for (int off = 1; off < 64; off <<= 1) {
    int t = __shfl_up(incl, off);
    if (lane >= off) incl += t;
  }
  if (lane == 63) wsum[wid] = incl;
  __syncthreads();
  if (wid == 0) {
    int nw = (int)(blockDim.x >> 6);
    int wv = (lane < nw) ? wsum[lane] : 0;
    int wi = wv;
#pragma unroll
    for (int off = 1; off < 16; off <<= 1) {
      int t = __shfl_up(wi, off);
      if (lane >= off) wi += t;
    }
    if (lane < nw) wsum[lane] = wi - wv;  // exclusive wave offsets
  }
  __syncthreads();
  return incl + wsum[wid];
}

// ---------------- colscan: per-bucket scan of partials over chunks ---------
__global__ __launch_bounds__(256) void k_colscan(const int* __restrict__ partials,
                                                 int* __restrict__ colscanT,
                                                 int* __restrict__ bktfill,
                                                 int nb, int sb) {
  int lane = threadIdx.x & 63, w = threadIdx.x >> 6;
  int b = blockIdx.x * 4 + w;
  if (b >= nb) return;
  int carry = 0;
  for (int ci0 = 0; ci0 < sb; ci0 += 64) {
    int ci = ci0 + lane;
    int v = (ci < sb) ? partials[(size_t)ci * nb + b] : 0;
    int incl = v;
#pragma unroll
    for (int off = 1; off < 64; off <<= 1) {
      int t = __shfl_up(incl, off);
      if (lane >= off) incl += t;
    }
    if (ci < sb) colscanT[(size_t)b * sb + ci] = carry + incl - v;
    carry += __shfl(incl, 63);
  }
  if (lane == 0) bktfill[b] = carry;
}

// ---------------- sortscan: scan bucket totals -> bases ----------------
__global__ __launch_bounds__(1024) void k_sortscan(const int* __restrict__ bktfill,
                                                   int* __restrict__ bktbase,
                                                   int nb, int* __restrict__ rp,
                                                   int n, int nnz) {
  __shared__ int wsum[16];
  int tid = threadIdx.x;
  int v = (tid < nb) ? bktfill[tid] : 0;
  int incl = block_incl_scan(v, wsum);
  if (tid < nb) bktbase[tid] = incl - v;
  if (tid == 0) rp[n] = nnz;
}

// ---------------- scatter3: edges -> bucket-partitioned staging ------------
__global__ __launch_bounds__(256) void k_scatter3(const int* __restrict__ Ar,
                                                  const int* __restrict__ Ac,
                                                  const float* __restrict__ Av,
                                                  const int* __restrict__ colscanT,
                                                  uint2* __restrict__ tmp,
                                                  int nnz, int nb, int cap, int sb) {
  __shared__ int cursor[MAXNB];
  int tid = threadIdx.x, bi = blockIdx.x;
  for (int t = tid; t < nb; t += 256)
    cursor[t] = t * cap + colscanT[(size_t)t * sb + bi];
  __syncthreads();
  int base = bi * CHUNK;
  int cnt = min(CHUNK, nnz - base);
  for (int it = 0; it < CHUNK / 256; ++it) {
    int k = it * 256 + tid;
    if (k < cnt) {
      int i = base + k;
      int r = Ar[i];
      int bkt = r >> BSHIFT;
      unsigned uq = (unsigned)fminf(Av[i] * 32768.f + 0.5f, 32767.f);
      int pos = atomicAdd(&cursor[bkt], 1);
      if (pos < (bkt + 1) * cap)
        tmp[pos] = make_uint2(((unsigned)Ac[i] << 15) | uq, (unsigned)r);
    }
  }
}

// ---------------- sort3: per-bucket CSR finalize (two-pass, LDS only) ------
__global__ __launch_bounds__(1024) void k_sort3(const uint2* __restrict__ tmp,
                                                const int* __restrict__ bktfill,
                                                const int* __restrict__ bktbase,
                                                unsigned* __restrict__ ccv,
                                                int* __restrict__ rp,
                                                int n, int cap) {
  __shared__ int rcnt[BROWS];
  __shared__ int rbase[BROWS];
  int b = blockIdx.x, tid = threadIdx.x;
  int cnt = min(bktfill[b], cap);
  const uint2* src = tmp + (size_t)b * cap;
  int bbase = bktbase[b];
  if (tid < BROWS) rcnt[tid] = 0;
  __syncthreads();

  // pass A: count local rows
  for (int i = tid; i < cnt; i += 1024)
    atomicAdd(&rcnt[src[i].y & (BROWS - 1)], 1);
  __syncthreads();

  // Hillis-Steele inclusive scan of rcnt[BROWS]
  int own = (tid < BROWS) ? rcnt[tid] : 0;
  for (int off = 1; off < BROWS; off <<= 1) {
    int v = 0;
    if (tid < BROWS) {
      v = rcnt[tid];
      if (tid >= off) v += rcnt[tid - off];
    }
    __syncthreads();
    if (tid < BROWS) rcnt[tid] = v;
    __syncthreads();
  }
  if (tid < BROWS) {
    int ex = rcnt[tid] - own;  // exclusive
    rbase[tid] = ex;
    int row = b * BROWS + tid;
    if (row < n) rp[row] = bbase + ex;
  }
  __syncthreads();
  if (tid < BROWS) rcnt[tid] = rbase[tid];  // reset as cursors
  __syncthreads();

  // pass B: re-read (L2-hot) and place
  for (int i = tid; i < cnt; i += 1024) {
    uint2 rr = src[i];
    int p = atomicAdd(&rcnt[rr.y & (BROWS - 1)], 1);
    ccv[bbase + p] = rr.x;
  }
}

// ---------------- MFMA GEMM + fused w1->fp8 + fused sort P1 (hist only) ----
#define BM 256
__global__ __launch_bounds__(256) void k_gemm(const float* __restrict__ X,
                                              const float* __restrict__ w1,
                                              const float* __restrict__ W,
                                              __half* __restrict__ xw16,
                                              unsigned char* __restrict__ w1f8, int n,
                                              const int* __restrict__ Ar,
                                              int* __restrict__ partials,
                                              int nnz, int nb, int sortB) {
  __shared__ char smem[32768];
  int tid = threadIdx.x;

  if (blockIdx.x < sortB) {  // ---- sort P1: per-chunk histogram ----
    int* hist = (int*)smem;  // nb ints
    int bi = blockIdx.x;
    int base = bi * CHUNK;
    int cnt = min(CHUNK, nnz - base);
    for (int t = tid; t < nb; t += 256) hist[t] = 0;
    __syncthreads();
    for (int it = 0; it < CHUNK / 256; ++it) {
      int k = it * 256 + tid;
      if (k < cnt) atomicAdd(&hist[Ar[base + k] >> BSHIFT], 1);
    }
    __syncthreads();
    for (int t = tid; t < nb; t += 256)
      partials[(size_t)bi * nb + t] = hist[t];  // coalesced plain store
    return;
  }

  // ---- GEMM part ----
  __half* lds = (__half*)smem;  // 32 KB swizzled W^T
  for (int t = tid; t < 2048; t += 256) {
    int nn = t >> 4, kg = t & 15;
    union { _Float16 h[8]; uint4 u; } u;
#pragma unroll
    for (int j = 0; j < 8; ++j) u.h[j] = (_Float16)W[(kg * 8 + j) * 128 + nn];
    int byte = nn * 256 + ((kg * 16) ^ ((nn & 7) << 4));
    *(uint4*)((char*)lds + byte) = u.u;
  }

  // fused w1 -> fp8(x128) for this block's rows
  long r0 = (long)(blockIdx.x - sortB) * BM;
  for (int i = tid; i < BM * 16; i += 256) {
    int rr = i >> 4, gg = i & 15;
    long r = r0 + rr;
    if (r < n) {
      const float* src = w1 + r * 128 + gg * 8;
      float4 f0 = *(const float4*)src;
      float4 f1 = *(const float4*)(src + 4);
      int lo = __builtin_amdgcn_cvt_pk_fp8_f32(f0.x * W1SCALE, f0.y * W1SCALE, 0, false);
      lo = __builtin_amdgcn_cvt_pk_fp8_f32(f0.z * W1SCALE, f0.w * W1SCALE, lo, true);
      int hi = __builtin_amdgcn_cvt_pk_fp8_f32(f1.x * W1SCALE, f1.y * W1SCALE, 0, false);
      hi = __builtin_amdgcn_cvt_pk_fp8_f32(f1.z * W1SCALE, f1.w * W1SCALE, hi, true);
      uint2 st = {(unsigned)lo, (unsigned)hi};
      *(uint2*)(w1f8 + r * 128 + gg * 8) = st;
    }
  }
  __syncthreads();

  int wid = tid >> 6, lane = tid & 63;
  int g = lane >> 4, lm = lane & 15;
  long rowbase = r0 + wid * 64;

  // A fragments: afr[m][kk], lane holds row (lm), k = kk*32 + g*8 + j
  f16x8 afr[4][4];
#pragma unroll
  for (int m = 0; m < 4; ++m) {
    long r = rowbase + m * 16 + lm;
    if (r >= n) r = n - 1;
    const float* xp = X + r * 128 + g * 8;
#pragma unroll
    for (int kk = 0; kk < 4; ++kk) {
      float4 lo = *(const float4*)(xp + kk * 32);
      float4 hi = *(const float4*)(xp + kk * 32 + 4);
      f16x8 a;
      a[0] = (_Float16)lo.x; a[1] = (_Float16)lo.y;
      a[2] = (_Float16)lo.z; a[3] = (_Float16)lo.w;
      a[4] = (_Float16)hi.x; a[5] = (_Float16)hi.y;
      a[6] = (_Float16)hi.z; a[7] = (_Float16)hi.w;
      afr[m][kk] = a;
    }
  }

#pragma unroll
  for (int nt = 0; nt < 8; ++nt) {
    int nn = nt * 16 + lm;
    int sw = (nn & 7) << 4;
    f16x8 bfr[4];
#pragma unroll
    for (int kk = 0; kk < 4; ++kk) {
      int byte = nn * 256 + ((kk * 64 + g * 16) ^ sw);
      bfr[kk] = *(f16x8*)((char*)lds + byte);
    }
#pragma unroll
    for (int m = 0; m < 4; ++m) {
      f32x4 acc = {0.f, 0.f, 0.f, 0.f};
#pragma unroll
      for (int kk = 0; kk < 4; ++kk)
        acc = __builtin_amdgcn_mfma_f32_16x16x32_f16(afr[m][kk], bfr[kk], acc, 0, 0, 0);
      // D: col = nn, row = rowbase + m*16 + g*4 + r (2B stores; L2 coalesces)
#pragma unroll
      for (int r = 0; r < 4; ++r) {
        long row = rowbase + m * 16 + g * 4 + r;
        if (row < n) xw16[row * 128 + nn] = __float2half(acc[r]);
      }
    }
  }
}

// ---------------- fused dual spmm + relu + highway gate --------------------
// one wave per row. Lane owns features {2l,2l+1}: per edge one full-wave
// ushort load (fp8 w1 row, 128B) + one full-wave uint load (f16 xw row,
// 256B). Branchless; scalar-broadcast metadata. y stored as per-row-scaled
// int8 (wave max-reduce for the scale; 128B row + 1 float scale).
__global__ __launch_bounds__(256) void k_spmm_ab(const int* __restrict__ rp,
                                                 const unsigned* __restrict__ ccv,
                                                 const unsigned char* __restrict__ w1f8,
                                                 const __half* __restrict__ xw16,
                                                 const float* __restrict__ wg,
                                                 unsigned char* __restrict__ y8,
                                                 float* __restrict__ yscl, int n) {
  int row = (int)((blockIdx.x * 256 + threadIdx.x) >> 6);
  int lane = threadIdx.x & 63;
  if (row >= n) return;
  int s = rp[row], e = rp[row + 1];
  const unsigned char* aptr = w1f8 + lane * 2;   // 2 fp8 features per lane
  const __half* bptr = xw16 + lane * 2;          // 2 f16 features per lane
  float aa0 = 0.f, aa1 = 0.f, bb0 = 0.f, bb1 = 0.f;

#define AB_EDGE(J)                                                         \
  {                                                                        \
    unsigned mm = (unsigned)__builtin_amdgcn_readlane((int)mr, (J));       \
    unsigned col = mm >> 15;                                               \
    float vq = (float)(mm & 0x7fffu);                                      \
    unsigned ua = *(const unsigned short*)(aptr + (size_t)col * 128);      \
    unsigned ub = *(const unsigned*)((const char*)bptr + (size_t)col * 256); \
    f32x2 fa = __builtin_amdgcn_cvt_pk_f32_fp8(ua, false);                 \
    float2 fb = __half22float2(*(__half2*)&ub);                            \
    aa0 = fmaf(vq, fa[0], aa0); aa1 = fmaf(vq, fa[1], aa1);                \
    bb0 = fmaf(vq, fb.x, bb0); bb1 = fmaf(vq, fb.y, bb1);                  \
  }

  for (int chunk = s; chunk < e; chunk += 64) {
    int idx = chunk + lane;
    unsigned mr = (idx < e) ? ccv[idx] : 0u;
    int cl = min(64, e - chunk);
    int j = 0;
    for (; j + 3 < cl; j += 4) {
      AB_EDGE(j) AB_EDGE(j + 1) AB_EDGE(j + 2) AB_EDGE(j + 3)
    }
    for (; j < cl; ++j) AB_EDGE(j)
  }
#undef AB_EDGE

  // rescale + relu
  float a0 = fmaxf(aa0 * AF, 0.f), a1 = fmaxf(aa1 * AF, 0.f);
  float b0 = fmaxf(bb0 * VSCL, 0.f), b1 = fmaxf(bb1 * VSCL, 0.f);

  // gate: T = sigmoid(dot(b, wg)) -- full-wave reduce
  float2 wgv = *(const float2*)(wg + lane * 2);
  float part = b0 * wgv.x + b1 * wgv.y;
#pragma unroll
  for (int off = 32; off > 0; off >>= 1) part += __shfl_xor(part, off);
  float T = 1.f / (1.f + __expf(-part));
  float u = 1.f - T;

  float y0 = T * a0 + u * b0;
  float y1 = T * a1 + u * b1;

  // per-row int8 quantization: wave max-reduce, scale = 255/max
  float m = fmaxf(y0, y1);
#pragma unroll
  for (int off = 32; off > 0; off >>= 1) m = fmaxf(m, __shfl_xor(m, off));
  float scl = (m > 0.f) ? 255.f / m : 0.f;
  unsigned q0 = min((unsigned)(y0 * scl + 0.5f), 255u);
  unsigned q1 = min((unsigned)(y1 * scl + 0.5f), 255u);
  *(unsigned short*)(y8 + (size_t)row * 128 + lane * 2) =
      (unsigned short)(q0 | (q1 << 8));
  if (lane == 0) yscl[row] = m * (1.f / 255.f);
}

// ---------------- final spmm: out = A @ y ----------------------------------
// one wave per row; full wave gathers one y8 row per edge (64 lanes x 2B =
// 128B = ONE line). Per-edge scalar yscl[col] load (SGPR via readlane).
__global__ __launch_bounds__(256) void k_spmm_out(const int* __restrict__ rp,
                                                  const unsigned* __restrict__ ccv,
                                                  const unsigned char* __restrict__ y8,
                                                  const float* __restrict__ yscl,
                                                  float* __restrict__ out, int n) {
  int row = (int)((blockIdx.x * 256 + threadIdx.x) >> 6);
  int lane = threadIdx.x & 63;
  if (row >= n) return;
  int s = rp[row], e = rp[row + 1];
  const unsigned char* ysub = y8 + lane * 2;
  float ac0 = 0.f, ac1 = 0.f;

#define OUT_EDGE(J)                                                        \
  {                                                                        \
    unsigned mm = (unsigned)__builtin_amdgcn_readlane((int)mr, (J));       \
    unsigned col = mm >> 15;                                               \
    float vs = (float)(mm & 0x7fffu) * yscl[col];                          \
    unsigned u = *(const unsigned short*)(ysub + (size_t)col * 128);       \
    ac0 = fmaf(vs, (float)(u & 255u), ac0);                                \
    ac1 = fmaf(vs, (float)(u >> 8), ac1);                                  \
  }

  for (int chunk = s; chunk < e; chunk += 64) {
    int idx = chunk + lane;
    unsigned mr = (idx < e) ? ccv[idx] : 0u;
    int cl = min(64, e - chunk);
    int j = 0;
    for (; j + 3 < cl; j += 4) {
      OUT_EDGE(j) OUT_EDGE(j + 1) OUT_EDGE(j + 2) OUT_EDGE(j + 3)
    }
    for (; j < cl; ++j) OUT_EDGE(j)
  }
#undef OUT_EDGE

  union { float2 f2; long long ll; } ov;
  ov.f2.x = ac0 * VSCL;
  ov.f2.y = ac1 * VSCL;
  __builtin_nontemporal_store(ov.ll, (long long*)(out + (size_t)row * 128 + lane * 2));
}

// ---------------------------------------------------------------------------
extern "C" void kernel_launch(void* const* d_in, const int* in_sizes, int n_in,
                              void* d_out, int out_size, void* d_ws, size_t ws_size,
                              hipStream_t stream) {
  const float* X  = (const float*)d_in[0];
  const float* w1 = (const float*)d_in[1];
  const float* w2 = (const float*)d_in[2];
  const float* wg = (const float*)d_in[3];
  const float* Av = (const float*)d_in[4];
  const int*   Ar = (const int*)d_in[5];
  const int*   Ac = (const int*)d_in[6];
  float* out = (float*)d_out;
  int N   = in_sizes[0] / 128;
  int NNZ = in_sizes[4];

  int NB    = (N + BROWS - 1) >> BSHIFT;    // 512-row buckets
  int sortB = (NNZ + CHUNK - 1) / CHUNK;    // chunks
  int cap   = (NNZ / NB) * 3 / 2 + 256;     // bucket staging capacity

  char* p = (char*)d_ws;
  auto alloc = [&](size_t b) {
    char* r = p;
    p += (b + 255) & ~(size_t)255;
    return r;
  };
  int*            rp       = (int*)alloc((size_t)(N + 1) * 4);
  int*            partials = (int*)alloc((size_t)sortB * NB * 4);
  int*            colscanT = (int*)alloc((size_t)NB * sortB * 4);
  int*            bktfill  = (int*)alloc((size_t)NB * 4);
  int*            bktbase  = (int*)alloc((size_t)NB * 4);
  uint2*          tmp      = (uint2*)alloc((size_t)NB * cap * 8);
  unsigned*       ccv      = (unsigned*)alloc((size_t)NNZ * 4);
  __half*         xw16     = (__half*)alloc((size_t)N * 128 * 2);
  unsigned char*  w1f8     = (unsigned char*)alloc((size_t)N * 128);
  unsigned char*  y8       = (unsigned char*)alloc((size_t)N * 128);
  float*          yscl     = (float*)alloc((size_t)N * 4);

  int gemmB = (N + BM - 1) / BM;
  k_gemm<<<sortB + gemmB, 256, 0, stream>>>(X, w1, w2, xw16, w1f8, N,
                                            Ar, partials, NNZ, NB, sortB);
  k_colscan<<<(NB + 3) / 4, 256, 0, stream>>>(partials, colscanT, bktfill, NB, sortB);
  k_sortscan<<<1, 1024, 0, stream>>>(bktfill, bktbase, NB, rp, N, NNZ);
  k_scatter3<<<sortB, 256, 0, stream>>>(Ar, Ac, Av, colscanT, tmp, NNZ, NB, cap, sortB);
  k_sort3<<<NB, 1024, 0, stream>>>(tmp, bktfill, bktbase, ccv, rp, N, cap);
  int wb = (N + 3) / 4;  // one 64-lane wave per row, 4 rows per 256-thread block
  k_spmm_ab<<<wb, 256, 0, stream>>>(rp, ccv, w1f8, xw16, wg, y8, yscl, N);
  k_spmm_out<<<wb, 256, 0, stream>>>(rp, ccv, y8, yscl, out, N);
}